// Round 9
// baseline (3137.570 us; speedup 1.0000x reference)
//
#include <hip/hip_runtime.h>
#include <hip/hip_bf16.h>

#define Bdim 64
#define Sdim 2048
#define Hdim 256

typedef __attribute__((ext_vector_type(8))) short short8;
typedef __attribute__((ext_vector_type(4))) float f32x4;

static __device__ __forceinline__ unsigned short f2bf(float f) {
  union { float f; unsigned int u; } v; v.f = f;
  unsigned int r = v.u + 0x7fffu + ((v.u >> 16) & 1u);  // RNE
  return (unsigned short)(r >> 16);
}
static __device__ __forceinline__ float bf2f(unsigned short u) {
  union { unsigned int u; float f; } v; v.u = ((unsigned int)u) << 16;
  return v.f;
}
static __device__ __forceinline__ float bflo(unsigned int u) {
  union { unsigned int u; float f; } v; v.u = u << 16; return v.f;
}
static __device__ __forceinline__ float bfhi(unsigned int u) {
  union { unsigned int u; float f; } v; v.u = u & 0xffff0000u; return v.f;
}

#if __has_builtin(__builtin_amdgcn_rcpf)
#define FAST_RCP(x) __builtin_amdgcn_rcpf(x)
#else
#define FAST_RCP(x) (1.0f / (x))
#endif

// tanh(x) = 1 - 2/(1 + e^{2x}) : 5 ops, saturates correctly at +/-inf.
static __device__ __forceinline__ float tanh_fast(float x) {
  float e = exp2f(x * 2.8853900817779268f);  // e^{2x}
  return 1.0f - 2.0f * FAST_RCP(1.0f + e);
}

#define STEP_BAR() do { __builtin_amdgcn_sched_barrier(0); \
    asm volatile("s_waitcnt lgkmcnt(0)" ::: "memory"); \
    __builtin_amdgcn_s_barrier(); \
    __builtin_amdgcn_sched_barrier(0); } while (0)

// ---------------------------------------------------------------------------
// Phase 2: sequential scan, MFMA transposed (D = W_hh . h^T), PIPELINED.
// 2 blocks x 512 threads (8 waves); block = 32 batches in two groups of 16
// (G0 = bs..bs+15 on D-cols l15, G1 = bs+16..bs+31). Two phases per step:
//   P1(t): MFMA-A(t)=W.h_G0(t-1)  ||  tanh-B(t-1), h_G1 writes, xwG0 prefetch
//   P2(t): MFMA-B(t)=W.h_G1(t-1)  ||  tanh-A(t),   h_G0 writes, xwG1 prefetch
// MFMA pipe (~620 cyc/phase) overlaps trans/VALU/LDS of the other group.
// LDS: 4 tiles (group x dbuf) of 16 rows x 512B, XOR-swizzled (device-verified
// layout). h stored bf16 to ws2 for phase 3; barrier = lgkm-only.
// ---------------------------------------------------------------------------
__global__ __launch_bounds__(512, 1) void rnn_scan_pipe(
    const unsigned short* __restrict__ xwh,   // bf16 xw [B][S][H]
    const float* __restrict__ Whh,
    unsigned short* __restrict__ ws2,         // bf16 h history [B][S][H]
    float* __restrict__ hfin) {
  __shared__ __align__(16) char lds[32768];   // tile(g,buf) at g*16384+buf*8192
  const int tid = threadIdx.x;
  const int lane = tid & 63;
  const int wv = tid >> 6;     // wave 0..7 -> n-cols wv*32..+31
  const int l15 = lane & 15;   // batch-within-group (D col) / W-row selector
  const int g = lane >> 4;     // 0..3
  const int bs = blockIdx.x * 32;

  // zero the slot-0 tiles (h0 = 0); slot-1 tiles are written before read
  {
    uint4 z; z.x = z.y = z.z = z.w = 0;
    ((uint4*)(lds))[tid] = z;            // tile(G0,0)
    ((uint4*)(lds + 16384))[tid] = z;    // tile(G1,0)
  }

  // A-frags (W_hh): lane (l15,g) holds W_hh[n][k], n = wv*32+tau*16+l15,
  // k = ks*32+g*8+e  (device-verified packing, r5/r7).
  short8 wfrag[2][8];
#pragma unroll
  for (int tau = 0; tau < 2; ++tau) {
    int n = wv * 32 + tau * 16 + l15;
#pragma unroll
    for (int ks = 0; ks < 8; ++ks) {
      int k0 = ks * 32 + g * 8;
      const float* p = Whh + n * 256 + k0;
      short8 v;
#pragma unroll
      for (int e = 0; e < 8; ++e) v[e] = (short)f2bf(p[e]);
      wfrag[tau][ks] = v;
    }
  }

  // B-frag (h) LDS byte offsets within a tile (device-verified swizzle)
  int aroff[8];
#pragma unroll
  for (int ks = 0; ks < 8; ++ks)
    aroff[ks] = l15 * 512 + ((ks * 64 + g * 16) ^ ((l15 & 7) << 4));

  // Per-thread outputs: n = wv*32 + tau*16 + g*4 + e (e consecutive)
  int nb[2], wo[2];
#pragma unroll
  for (int tau = 0; tau < 2; ++tau) {
    nb[tau] = wv * 32 + tau * 16 + g * 4;
    wo[tau] = l15 * 512 + ((2 * nb[tau]) ^ ((l15 & 7) << 4));
  }

  const long bG0 = bs + l15, bG1 = bs + 16 + l15;
  const long baseA = bG0 * Sdim * Hdim;
  const long baseB = bG1 * Sdim * Hdim;

  // xw register buffers (bf16 pairs), depth-2 prefetch
  uint2 xwAc[2], xwAn[2], xwBc[2], xwBn[2];
#pragma unroll
  for (int tau = 0; tau < 2; ++tau) {
    xwAc[tau] = *(const uint2*)(xwh + baseA + nb[tau]);
    xwBc[tau] = *(const uint2*)(xwh + baseB + nb[tau]);
  }

  f32x4 accA[2], accB[2];

  __syncthreads();  // zeros + (single full drain outside the loop)

  auto substep = [&](int t, int buf) {
    // ------------- P1: MFMA-A(t) || tanh-B(t-1) -------------
    {
#pragma unroll
      for (int tau = 0; tau < 2; ++tau) {   // C-init = xw_G0(t)
        accA[tau][0] = bflo(xwAc[tau].x); accA[tau][1] = bfhi(xwAc[tau].x);
        accA[tau][2] = bflo(xwAc[tau].y); accA[tau][3] = bfhi(xwAc[tau].y);
      }
      const char* tA = lds + buf * 8192;    // tile(G0, t&1)
#pragma unroll
      for (int ks = 0; ks < 8; ++ks) {
        short8 h8 = *(const short8*)(tA + aroff[ks]);
        accA[0] = __builtin_amdgcn_mfma_f32_16x16x32_bf16(wfrag[0][ks], h8, accA[0], 0, 0, 0);
        accA[1] = __builtin_amdgcn_mfma_f32_16x16x32_bf16(wfrag[1][ks], h8, accA[1], 0, 0, 0);
      }
      if (t > 0) {                          // finish G1 step t-1
        char* wB = lds + 16384 + buf * 8192;  // tile(G1, t&1), read by P2(t)
#pragma unroll
        for (int tau = 0; tau < 2; ++tau) {
          f32x4 v;
#pragma unroll
          for (int e = 0; e < 4; ++e) v[e] = tanh_fast(accB[tau][e]);
          uint2 p;
          asm("v_cvt_pk_bf16_f32 %0, %1, %2" : "=v"(p.x) : "v"(v[0]), "v"(v[1]));
          asm("v_cvt_pk_bf16_f32 %0, %1, %2" : "=v"(p.y) : "v"(v[2]), "v"(v[3]));
          *(uint2*)(wB + wo[tau]) = p;
          *(uint2*)(ws2 + baseB + (long)(t - 1) * Hdim + nb[tau]) = p;
        }
      }
      if (t + 1 < Sdim) {                   // prefetch xw_G0(t+1)
#pragma unroll
        for (int tau = 0; tau < 2; ++tau)
          xwAn[tau] = *(const uint2*)(xwh + baseA + (long)(t + 1) * Hdim + nb[tau]);
      }
    }
    STEP_BAR();
    // ------------- P2: MFMA-B(t) || tanh-A(t) -------------
    {
#pragma unroll
      for (int tau = 0; tau < 2; ++tau) {   // C-init = xw_G1(t)
        accB[tau][0] = bflo(xwBc[tau].x); accB[tau][1] = bfhi(xwBc[tau].x);
        accB[tau][2] = bflo(xwBc[tau].y); accB[tau][3] = bfhi(xwBc[tau].y);
      }
      const char* tB = lds + 16384 + buf * 8192;  // tile(G1, t&1)
#pragma unroll
      for (int ks = 0; ks < 8; ++ks) {
        short8 h8 = *(const short8*)(tB + aroff[ks]);
        accB[0] = __builtin_amdgcn_mfma_f32_16x16x32_bf16(wfrag[0][ks], h8, accB[0], 0, 0, 0);
        accB[1] = __builtin_amdgcn_mfma_f32_16x16x32_bf16(wfrag[1][ks], h8, accB[1], 0, 0, 0);
      }
      {                                     // finish G0 step t
        char* wA = lds + (buf ^ 1) * 8192;  // tile(G0, (t+1)&1), read by P1(t+1)
#pragma unroll
        for (int tau = 0; tau < 2; ++tau) {
          f32x4 v;
#pragma unroll
          for (int e = 0; e < 4; ++e) v[e] = tanh_fast(accA[tau][e]);
          uint2 p;
          asm("v_cvt_pk_bf16_f32 %0, %1, %2" : "=v"(p.x) : "v"(v[0]), "v"(v[1]));
          asm("v_cvt_pk_bf16_f32 %0, %1, %2" : "=v"(p.y) : "v"(v[2]), "v"(v[3]));
          *(uint2*)(wA + wo[tau]) = p;
          *(uint2*)(ws2 + baseA + (long)t * Hdim + nb[tau]) = p;
          if (t == Sdim - 1) *(f32x4*)(hfin + bG0 * Hdim + nb[tau]) = v;
        }
      }
      if (t + 1 < Sdim) {                   // prefetch xw_G1(t+1)
#pragma unroll
        for (int tau = 0; tau < 2; ++tau)
          xwBn[tau] = *(const uint2*)(xwh + baseB + (long)(t + 1) * Hdim + nb[tau]);
      }
#pragma unroll
      for (int tau = 0; tau < 2; ++tau) { xwAc[tau] = xwAn[tau]; xwBc[tau] = xwBn[tau]; }
    }
    STEP_BAR();
  };

  for (int t = 0; t < Sdim; t += 2) {
    substep(t, 0);
    substep(t + 1, 1);
  }

  // epilogue: finish G1 step Sdim-1 (accB from the final P2)
#pragma unroll
  for (int tau = 0; tau < 2; ++tau) {
    f32x4 v;
#pragma unroll
    for (int e = 0; e < 4; ++e) v[e] = tanh_fast(accB[tau][e]);
    uint2 p;
    asm("v_cvt_pk_bf16_f32 %0, %1, %2" : "=v"(p.x) : "v"(v[0]), "v"(v[1]));
    asm("v_cvt_pk_bf16_f32 %0, %1, %2" : "=v"(p.y) : "v"(v[2]), "v"(v[3]));
    *(uint2*)(ws2 + baseB + (long)(Sdim - 1) * Hdim + nb[tau]) = p;
    *(f32x4*)(hfin + bG1 * Hdim + nb[tau]) = v;
  }
}

// ---------------------------------------------------------------------------
// Fallback scan (tiny workspace): fused VALU version — known-good from round 3.
// ---------------------------------------------------------------------------
__global__ __launch_bounds__(256, 1) void rnn_scan_valu_fused(
    const float* __restrict__ x, const float* __restrict__ Wih,
    const float* __restrict__ bh, const float* __restrict__ Whh,
    float* __restrict__ hout, float* __restrict__ hfin) {
  __shared__ __align__(16) uint2 wt[64][256];
  __shared__ __align__(16) float hl[256];
  const int n = threadIdx.x;
  const int b = blockIdx.x;
  {
    const float2* src = (const float2*)Whh;
    unsigned int* w32 = (unsigned int*)wt;
    for (int i = n; i < 32768; i += 256) {
      float2 f = src[i];
      unsigned int u = (unsigned int)f2bf(f.x) | ((unsigned int)f2bf(f.y) << 16);
      int row = i >> 7, kk = i & 127, k4 = kk >> 1, half = kk & 1;
      w32[k4 * 512 + row * 2 + half] = u;
    }
  }
  hl[n] = 0.0f;
  __syncthreads();
  const long base = (long)b * Sdim * Hdim + n;
  for (int t = 0; t < Sdim; ++t) {
    const float* xr = x + ((long)b * Sdim + t) * 256;
    const float* wr = Wih + n * 256;
    float acc = bh[n];
    for (int k = 0; k < 256; ++k) acc += xr[k] * wr[k];
#pragma unroll 8
    for (int k4 = 0; k4 < 64; ++k4) {
      uint2 w2 = wt[k4][n];
      float4 h4 = *(const float4*)&hl[k4 * 4];
      acc += bflo(w2.x) * h4.x + bfhi(w2.x) * h4.y
           + bflo(w2.y) * h4.z + bfhi(w2.y) * h4.w;
    }
    float hv = tanh_fast(acc);
    __syncthreads();
    hl[n] = hv;
    hout[base + (long)t * Hdim] = hv;
    if (t == Sdim - 1) hfin[b * Hdim + n] = hv;
    __syncthreads();
  }
}

// ---------------------------------------------------------------------------
// Phases 1 & 3: out[r,n] = A[r,:] @ W[n,:] + bias[n], A is [131072,256].
// 512 thr (8 waves), 128 rows/block; W fully staged in STATIC LDS (bf16,
// XOR-swizzled). A_F32: fp32 vs bf16 A; OUT_F32: fp32 vs bf16 out.
// ---------------------------------------------------------------------------
template<int A_F32, int OUT_F32>
__global__ __launch_bounds__(512, 2) void gemm256(const void* __restrict__ Ap,
                                                  const float* __restrict__ Wf,
                                                  const float* __restrict__ bias,
                                                  void* __restrict__ outp) {
  __shared__ __align__(16) char wl[131072];
  const int tid = threadIdx.x;
  const int lane = tid & 63;
  const int wv = tid >> 6;
  const int l15 = lane & 15;
  const int g = lane >> 4;
  const long r0 = (long)blockIdx.x * 128;

  for (int i = tid; i < 256 * 64; i += 512) {
    int n = i >> 6;
    int kc = (i & 63) * 4;
    f32x4 c = *(const f32x4*)(Wf + n * 256 + kc);
    unsigned int lo = (unsigned int)f2bf(c[0]) | ((unsigned int)f2bf(c[1]) << 16);
    unsigned int hi = (unsigned int)f2bf(c[2]) | ((unsigned int)f2bf(c[3]) << 16);
    int kb = (kc * 2) ^ ((n & 7) << 4);
    unsigned int* dst = (unsigned int*)(wl + n * 512 + kb);
    dst[0] = lo; dst[1] = hi;
  }
  __syncthreads();

  f32x4 acc[16];
#pragma unroll
  for (int tau = 0; tau < 16; ++tau) {
    float bv = bias[tau * 16 + l15];
    acc[tau][0] = bv; acc[tau][1] = bv; acc[tau][2] = bv; acc[tau][3] = bv;
  }

  const long arow = r0 + wv * 16 + l15;
#pragma unroll
  for (int ks = 0; ks < 8; ++ks) {
    const int k0 = ks * 32 + g * 8;
    short8 a;
    if (A_F32) {
      const f32x4* ap = (const f32x4*)((const float*)Ap + arow * 256 + k0);
      f32x4 x0 = ap[0], x1 = ap[1];
#pragma unroll
      for (int e = 0; e < 4; ++e) { a[e] = (short)f2bf(x0[e]); a[4 + e] = (short)f2bf(x1[e]); }
    } else {
      a = *(const short8*)((const unsigned short*)Ap + arow * 256 + k0);
    }
#pragma unroll
    for (int tau = 0; tau < 16; ++tau) {
      int n = tau * 16 + l15;
      int kb = (k0 * 2) ^ ((n & 7) << 4);
      short8 b = *(const short8*)(wl + n * 512 + kb);
      acc[tau] = __builtin_amdgcn_mfma_f32_16x16x32_bf16(a, b, acc[tau], 0, 0, 0);
    }
  }

#pragma unroll
  for (int tau = 0; tau < 16; ++tau) {
    int n = tau * 16 + l15;
#pragma unroll
    for (int e = 0; e < 4; ++e) {
      long row = r0 + wv * 16 + g * 4 + e;
      if (OUT_F32) ((float*)outp)[row * 256 + n] = acc[tau][e];
      else         ((unsigned short*)outp)[row * 256 + n] = f2bf(acc[tau][e]);
    }
  }
}

extern "C" void kernel_launch(void* const* d_in, const int* in_sizes, int n_in,
                              void* d_out, int out_size, void* d_ws, size_t ws_size,
                              hipStream_t stream) {
  const float* x    = (const float*)d_in[0];
  const float* W_ih = (const float*)d_in[1];
  const float* W_hh = (const float*)d_in[2];
  const float* b_h  = (const float*)d_in[3];
  const float* W_ho = (const float*)d_in[4];
  const float* b_o  = (const float*)d_in[5];
  float* out  = (float*)d_out;
  float* hfin = out + (size_t)Bdim * Sdim * Hdim;

  const int gblocks = (Bdim * Sdim) / 128;                    // 1024
  const size_t half = (size_t)Bdim * Sdim * Hdim * 2;         // 64 MiB (bf16 plane)

  if (ws_size >= 2 * half) {
    unsigned short* ws1 = (unsigned short*)d_ws;              // bf16 xw
    unsigned short* ws2 = ws1 + (size_t)Bdim * Sdim * Hdim;   // bf16 h history
    gemm256<1, 0><<<gblocks, 512, 0, stream>>>(x, W_ih, b_h, ws1);   // phase 1
    rnn_scan_pipe<<<2, 512, 0, stream>>>(ws1, W_hh, ws2, hfin);      // phase 2
    gemm256<0, 1><<<gblocks, 512, 0, stream>>>(ws2, W_ho, b_o, out); // phase 3
  } else {
    rnn_scan_valu_fused<<<Bdim, 256, 0, stream>>>(x, W_ih, b_h, W_hh, out, hfin);
    gemm256<1, 1><<<gblocks, 512, 0, stream>>>(out, W_ho, b_o, out); // in place
  }
}